// Round 1
// baseline (2177.230 us; speedup 1.0000x reference)
//
#include <hip/hip_runtime.h>
#include <math.h>

// Residual VQ: x (262144,128) fp32, codebooks (3,256,128) fp32.
// Output: [indices as float (262144*3)] ++ [quantized (262144*128)].
//
// ARITHMETIC CONTRACT (round 3, absmax=0 — do not change):
//   M_k  = OpenBLAS sgemm K-loop: sequential FMA chain j=0..127, acc init 0
//   A    = np.sum(r*r): pairwise_sum 8-accumulator scheme, products rounded
//          separately (fmaf(x,x,0) = single-rounded product, blocks fusion)
//   d2_k = (A - 2.0f*M_k) + B_k ; argmin strict < ascending k
//   residual -= q ; quantized = (q0 + q1) + q2  (elementwise fp32, ref order)
//
// ROUND 5 CHANGE: residual held in 8 named ext_vector(16) SSA values.
// Round 4's counters showed VGPR_Count=104 (< the 128 floats of r[]) despite
// __launch_bounds__(256,1): SROA never promoted `float r[128]` (its address
// escaped into the pairwise lambda), so every FMA re-read the residual from
// scratch -> latency-bound, VALUBusy 39%, 6.1x the 327us FMA-issue floor.
// Named ext-vector values are pure SSA (no alloca, nothing to spill); all
// element accesses are compile-time-constant lanes. Codebook rows stay
// wave-uniform -> s_load into SGPRs (scalar pipe, free vs VALU); B_k is one
// float4 LDS broadcast per k-group.

constexpr int kItems = 262144;
constexpr int kDim   = 128;
constexpr int kNcb   = 3;
constexpr int kK     = 256;
constexpr int kBlock = 256;

typedef float vf16 __attribute__((ext_vector_type(16)));

__device__ __forceinline__ float sq_rn(float x) {
    return __builtin_fmaf(x, x, 0.0f);   // single-rounded product, no contraction
}

// numpy pairwise_sum of squares, n=128: 8 accumulators,
// acc_m = t(m)+t(8+m)+...+t(120+m), combined ((a0+a1)+(a2+a3))+((a4+a5)+(a6+a7))
__device__ __forceinline__ float np_sumsq128(const float* __restrict__ p) {
    float a0 = sq_rn(p[0]), a1 = sq_rn(p[1]), a2 = sq_rn(p[2]), a3 = sq_rn(p[3]),
          a4 = sq_rn(p[4]), a5 = sq_rn(p[5]), a6 = sq_rn(p[6]), a7 = sq_rn(p[7]);
    #pragma unroll
    for (int i = 8; i < 128; i += 8) {
        a0 = a0 + sq_rn(p[i + 0]); a1 = a1 + sq_rn(p[i + 1]);
        a2 = a2 + sq_rn(p[i + 2]); a3 = a3 + sq_rn(p[i + 3]);
        a4 = a4 + sq_rn(p[i + 4]); a5 = a5 + sq_rn(p[i + 5]);
        a6 = a6 + sq_rn(p[i + 6]); a7 = a7 + sq_rn(p[i + 7]);
    }
    return ((a0 + a1) + (a2 + a3)) + ((a4 + a5) + (a6 + a7));
}

// constant-folded residual-chunk selector (i is always a compile-time constant
// after full unrolling; pure SSA value select, no memory)
#define RC(i) ((i)==0?R0:(i)==1?R1:(i)==2?R2:(i)==3?R3:(i)==4?R4:(i)==5?R5:(i)==6?R6:R7)

__global__ __launch_bounds__(kBlock, 2) void rvq_kernel(
    const float* __restrict__ x,
    const float* __restrict__ cb,
    float* __restrict__ out)
{
    // B_k = np.sum(cb*cb, axis=-1), bit-exact, staged in LDS as float4 per k-group
    __shared__ float4 s_B4[kNcb * kK / 4];
    for (int m = threadIdx.x; m < kNcb * kK; m += kBlock)
        ((float*)s_B4)[m] = np_sumsq128(cb + (size_t)m * kDim);
    __syncthreads();

    const int item = blockIdx.x * kBlock + threadIdx.x;
    const vf16* xv = (const vf16*)(x + (size_t)item * kDim);
    vf16 R0 = xv[0], R1 = xv[1], R2 = xv[2], R3 = xv[3],
         R4 = xv[4], R5 = xv[5], R6 = xv[6], R7 = xv[7];

    int sel[kNcb];

    #pragma unroll
    for (int c = 0; c < kNcb; ++c) {
        const float* cbase = cb + (size_t)c * kK * kDim;

        // A = np.sum(r*r), pairwise-8 scheme, term order j = 8*i + m
        float a0, a1, a2, a3, a4, a5, a6, a7;
        {
            const vf16 rc = R0;
            a0 = sq_rn(rc[0]); a1 = sq_rn(rc[1]); a2 = sq_rn(rc[2]); a3 = sq_rn(rc[3]);
            a4 = sq_rn(rc[4]); a5 = sq_rn(rc[5]); a6 = sq_rn(rc[6]); a7 = sq_rn(rc[7]);
        }
        #pragma unroll
        for (int i = 1; i < 16; ++i) {
            const vf16 rc = RC(i >> 1);      // chunk (8i+m)>>4 == i>>1
            const int  b  = 8 * (i & 1);     // element (8i+m)&15 == 8*(i&1)+m
            a0 = a0 + sq_rn(rc[b + 0]); a1 = a1 + sq_rn(rc[b + 1]);
            a2 = a2 + sq_rn(rc[b + 2]); a3 = a3 + sq_rn(rc[b + 3]);
            a4 = a4 + sq_rn(rc[b + 4]); a5 = a5 + sq_rn(rc[b + 5]);
            a6 = a6 + sq_rn(rc[b + 6]); a7 = a7 + sq_rn(rc[b + 7]);
        }
        const float A = ((a0 + a1) + (a2 + a3)) + ((a4 + a5) + (a6 + a7));

        float best = INFINITY;
        int bi = 0;
        // 4 independent sequential-FMA chains (ILP over the 4-cyc FMA latency);
        // codebook chunks are wave-uniform -> scalar loads, SGPR operands.
        for (int k = 0; k < kK; k += 4) {
            const vf16* c0v = (const vf16*)(cbase + (size_t)(k + 0) * kDim);
            const vf16* c1v = (const vf16*)(cbase + (size_t)(k + 1) * kDim);
            const vf16* c2v = (const vf16*)(cbase + (size_t)(k + 2) * kDim);
            const vf16* c3v = (const vf16*)(cbase + (size_t)(k + 3) * kDim);
            float m0 = 0.f, m1 = 0.f, m2 = 0.f, m3 = 0.f;
            #pragma unroll
            for (int i = 0; i < 8; ++i) {          // j = 16*i + e, ascending
                const vf16 rc = RC(i);
                const vf16 c0 = c0v[i];
                const vf16 c1 = c1v[i];
                const vf16 c2 = c2v[i];
                const vf16 c3 = c3v[i];
                #pragma unroll
                for (int e = 0; e < 16; ++e) {     // sgemm k-order: sequential FMA
                    m0 = __builtin_fmaf(rc[e], c0[e], m0);
                    m1 = __builtin_fmaf(rc[e], c1[e], m1);
                    m2 = __builtin_fmaf(rc[e], c2[e], m2);
                    m3 = __builtin_fmaf(rc[e], c3[e], m3);
                }
            }
            const float4 b4 = s_B4[c * (kK / 4) + (k >> 2)];
            float t0 = (A - 2.0f * m0) + b4.x;   // 2*m exact (pow2), contraction-safe
            float t1 = (A - 2.0f * m1) + b4.y;
            float t2 = (A - 2.0f * m2) + b4.z;
            float t3 = (A - 2.0f * m3) + b4.w;
            if (t0 < best) { best = t0; bi = k + 0; }
            if (t1 < best) { best = t1; bi = k + 1; }
            if (t2 < best) { best = t2; bi = k + 2; }
            if (t3 < best) { best = t3; bi = k + 3; }
        }
        sel[c] = bi;

        const vf16* cw = (const vf16*)(cbase + (size_t)bi * kDim);
        R0 = R0 - cw[0]; R1 = R1 - cw[1]; R2 = R2 - cw[2]; R3 = R3 - cw[3];
        R4 = R4 - cw[4]; R5 = R5 - cw[5]; R6 = R6 - cw[6]; R7 = R7 - cw[7];
    }

    // --- outputs
    float* out_idx = out;                             // (items, 3) as float
    float* out_q   = out + (size_t)kItems * kNcb;     // (items, 128)
    #pragma unroll
    for (int c = 0; c < kNcb; ++c)
        out_idx[(size_t)item * kNcb + c] = (float)sel[c];

    const vf16* q0 = (const vf16*)(cb + ((size_t)0 * kK + sel[0]) * kDim);
    const vf16* q1 = (const vf16*)(cb + ((size_t)1 * kK + sel[1]) * kDim);
    const vf16* q2 = (const vf16*)(cb + ((size_t)2 * kK + sel[2]) * kDim);
    vf16* qo = (vf16*)(out_q + (size_t)item * kDim);
    #pragma unroll
    for (int i = 0; i < 8; ++i)
        qo[i] = (q0[i] + q1[i]) + q2[i];   // ((0+q0)+q1)+q2 in fp32, ref order
}

extern "C" void kernel_launch(void* const* d_in, const int* in_sizes, int n_in,
                              void* d_out, int out_size, void* d_ws, size_t ws_size,
                              hipStream_t stream) {
    const float* x  = (const float*)d_in[0];
    const float* cb = (const float*)d_in[1];
    float* out = (float*)d_out;
    rvq_kernel<<<kItems / kBlock, kBlock, 0, stream>>>(x, cb, out);
}

// Round 2
// 1840.202 us; speedup vs baseline: 1.1831x; 1.1831x over previous
//
#include <hip/hip_runtime.h>
#include <math.h>

// Residual VQ: x (262144,128) fp32, codebooks (3,256,128) fp32.
// Output: [indices as float (262144*3)] ++ [quantized (262144*128)].
//
// ARITHMETIC CONTRACT (round 3, absmax=0 — do not change):
//   M_k  = OpenBLAS sgemm K-loop: sequential FMA chain j=0..127, acc init 0
//   A    = np.sum(r*r): pairwise_sum 8-accumulator scheme, products rounded
//          separately (fmaf(x,x,0) = single-rounded product, blocks fusion)
//   d2_k = (A - 2.0f*M_k) + B_k ; argmin strict < ascending k
//   residual -= q ; quantized = (q0 + q1) + q2  (elementwise fp32, ref order)
//
// ROUND 6 CHANGE: scalar float r[128], NO lambdas, all constant indices.
// History of where the residual actually lived:
//   r3/r4: float r[128] + [&] lambda -> address escaped -> SROA failed ->
//          scratch (VGPR=104, WRITE 180MB of spill, VALUBusy 39%).
//   r5:    8x ext_vector(16) SSA -> no scratch (WRITE down to 141MB) BUT
//          16-wide tuples need 16-contiguous aligned regs; RA resolved the
//          fragmentation by shuffling through AGPRs (VGPR=96 arch-only,
//          v_accvgpr moves are VALU -> VALUBusy 39->53%, dur flat).
// Fix: plain scalars promote to 128 INDEPENDENT SSA floats (no tuple
// constraint). launch_bounds(256,2) caps at 256 regs (2 waves/SIMD).
// Codebook rows stay wave-uniform -> s_load into SGPRs (scalar pipe);
// FMA = v_fma(v_r, s_c, v_acc), 1 SGPR operand is legal. #pragma unroll 2
// on the k-loop keeps one group of s_loads in flight ahead of the FMAs.

constexpr int kItems = 262144;
constexpr int kDim   = 128;
constexpr int kNcb   = 3;
constexpr int kK     = 256;
constexpr int kBlock = 256;

__device__ __forceinline__ float sq_rn(float x) {
    return __builtin_fmaf(x, x, 0.0f);   // single-rounded product, blocks contraction
}

// numpy pairwise_sum of squares, n=128: 8 accumulators,
// acc_m = t(m)+t(8+m)+...+t(120+m), combine ((a0+a1)+(a2+a3))+((a4+a5)+(a6+a7))
// (pointer version — used ONLY for codebook B_k; never touches r[])
__device__ __forceinline__ float np_sumsq128(const float* __restrict__ p) {
    float a0 = sq_rn(p[0]), a1 = sq_rn(p[1]), a2 = sq_rn(p[2]), a3 = sq_rn(p[3]),
          a4 = sq_rn(p[4]), a5 = sq_rn(p[5]), a6 = sq_rn(p[6]), a7 = sq_rn(p[7]);
    #pragma unroll
    for (int i = 8; i < 128; i += 8) {
        a0 = a0 + sq_rn(p[i + 0]); a1 = a1 + sq_rn(p[i + 1]);
        a2 = a2 + sq_rn(p[i + 2]); a3 = a3 + sq_rn(p[i + 3]);
        a4 = a4 + sq_rn(p[i + 4]); a5 = a5 + sq_rn(p[i + 5]);
        a6 = a6 + sq_rn(p[i + 6]); a7 = a7 + sq_rn(p[i + 7]);
    }
    return ((a0 + a1) + (a2 + a3)) + ((a4 + a5) + (a6 + a7));
}

__global__ __launch_bounds__(kBlock, 2) void rvq_kernel(
    const float* __restrict__ x,
    const float* __restrict__ cb,
    float* __restrict__ out)
{
    // B_k = np.sum(cb*cb, axis=-1), bit-exact, staged in LDS (float4 per k-group)
    __shared__ float4 s_B4[kNcb * kK / 4];
    for (int m = threadIdx.x; m < kNcb * kK; m += kBlock)
        ((float*)s_B4)[m] = np_sumsq128(cb + (size_t)m * kDim);
    __syncthreads();

    const int item = blockIdx.x * kBlock + threadIdx.x;
    const float* xp = x + (size_t)item * kDim;

    // residual: plain scalars, constant-indexed everywhere -> SROA promotes
    float r[kDim];
    #pragma unroll
    for (int i = 0; i < kDim / 4; ++i) {
        float4 v = ((const float4*)xp)[i];
        r[4*i+0] = v.x; r[4*i+1] = v.y; r[4*i+2] = v.z; r[4*i+3] = v.w;
    }

    int sel[kNcb];

    #pragma unroll
    for (int c = 0; c < kNcb; ++c) {
        const float* cbase = cb + (size_t)c * kK * kDim;

        // A = np.sum(r*r): pairwise-8, written inline (no lambda, no escape)
        float a0 = sq_rn(r[0]), a1 = sq_rn(r[1]), a2 = sq_rn(r[2]), a3 = sq_rn(r[3]),
              a4 = sq_rn(r[4]), a5 = sq_rn(r[5]), a6 = sq_rn(r[6]), a7 = sq_rn(r[7]);
        #pragma unroll
        for (int i = 8; i < kDim; i += 8) {
            a0 = a0 + sq_rn(r[i + 0]); a1 = a1 + sq_rn(r[i + 1]);
            a2 = a2 + sq_rn(r[i + 2]); a3 = a3 + sq_rn(r[i + 3]);
            a4 = a4 + sq_rn(r[i + 4]); a5 = a5 + sq_rn(r[i + 5]);
            a6 = a6 + sq_rn(r[i + 6]); a7 = a7 + sq_rn(r[i + 7]);
        }
        const float A = ((a0 + a1) + (a2 + a3)) + ((a4 + a5) + (a6 + a7));

        float best = INFINITY;
        int bi = 0;
        // 4 independent sequential-FMA chains (ILP covers 4-cyc FMA latency);
        // codebook rows wave-uniform -> SGPR operands via s_load.
        #pragma unroll 2
        for (int k = 0; k < kK; k += 4) {
            const float* c0 = cbase + (size_t)(k + 0) * kDim;
            const float* c1 = cbase + (size_t)(k + 1) * kDim;
            const float* c2 = cbase + (size_t)(k + 2) * kDim;
            const float* c3 = cbase + (size_t)(k + 3) * kDim;
            float m0 = 0.f, m1 = 0.f, m2 = 0.f, m3 = 0.f;
            #pragma unroll
            for (int j = 0; j < kDim; ++j) {   // sgemm k-order: sequential FMA
                m0 = __builtin_fmaf(r[j], c0[j], m0);
                m1 = __builtin_fmaf(r[j], c1[j], m1);
                m2 = __builtin_fmaf(r[j], c2[j], m2);
                m3 = __builtin_fmaf(r[j], c3[j], m3);
            }
            const float4 b4 = s_B4[c * (kK / 4) + (k >> 2)];
            // 2.0f*m is exact (exponent bump) -> sub rounds the same exact
            // value whether or not the compiler fuses; bit-safe either way.
            float t0 = (A - 2.0f * m0) + b4.x;
            float t1 = (A - 2.0f * m1) + b4.y;
            float t2 = (A - 2.0f * m2) + b4.z;
            float t3 = (A - 2.0f * m3) + b4.w;
            if (t0 < best) { best = t0; bi = k + 0; }
            if (t1 < best) { best = t1; bi = k + 1; }
            if (t2 < best) { best = t2; bi = k + 2; }
            if (t3 < best) { best = t3; bi = k + 3; }
        }
        sel[c] = bi;

        const float* cw = cbase + (size_t)bi * kDim;   // divergent gather
        #pragma unroll
        for (int i = 0; i < kDim / 4; ++i) {
            float4 v = ((const float4*)cw)[i];
            r[4*i+0] = r[4*i+0] - v.x;
            r[4*i+1] = r[4*i+1] - v.y;
            r[4*i+2] = r[4*i+2] - v.z;
            r[4*i+3] = r[4*i+3] - v.w;   // fp32, ref order
        }
    }

    // --- outputs
    float* out_idx = out;                             // (items, 3) as float
    float* out_q   = out + (size_t)kItems * kNcb;     // (items, 128)
    #pragma unroll
    for (int c = 0; c < kNcb; ++c)
        out_idx[(size_t)item * kNcb + c] = (float)sel[c];

    const float* q0 = cb + ((size_t)0 * kK + sel[0]) * kDim;
    const float* q1 = cb + ((size_t)1 * kK + sel[1]) * kDim;
    const float* q2 = cb + ((size_t)2 * kK + sel[2]) * kDim;
    float* qo = out_q + (size_t)item * kDim;
    #pragma unroll
    for (int i = 0; i < kDim / 4; ++i) {
        float4 v0 = ((const float4*)q0)[i];
        float4 v1 = ((const float4*)q1)[i];
        float4 v2 = ((const float4*)q2)[i];
        float4 w;
        w.x = (v0.x + v1.x) + v2.x;
        w.y = (v0.y + v1.y) + v2.y;
        w.z = (v0.z + v1.z) + v2.z;
        w.w = (v0.w + v1.w) + v2.w;   // ((0+q0)+q1)+q2 in fp32, ref order
        ((float4*)qo)[i] = w;
    }
}

extern "C" void kernel_launch(void* const* d_in, const int* in_sizes, int n_in,
                              void* d_out, int out_size, void* d_ws, size_t ws_size,
                              hipStream_t stream) {
    const float* x  = (const float*)d_in[0];
    const float* cb = (const float*)d_in[1];
    float* out = (float*)d_out;
    rvq_kernel<<<kItems / kBlock, kBlock, 0, stream>>>(x, cb, out);
}

// Round 3
// 1839.245 us; speedup vs baseline: 1.1838x; 1.0005x over previous
//
#include <hip/hip_runtime.h>
#include <math.h>

// Residual VQ: x (262144,128) fp32, codebooks (3,256,128) fp32.
// Output: [indices as float (262144*3)] ++ [quantized (262144*128)].
//
// ARITHMETIC CONTRACT (round 3, absmax=0 — do not change):
//   M_k  = OpenBLAS sgemm K-loop: sequential FMA chain j=0..127, acc init 0
//   A    = np.sum(r*r): pairwise_sum 8-accumulator scheme, products rounded
//          separately (fmaf(x,x,0) = single-rounded product, blocks fusion)
//   d2_k = (A - 2.0f*M_k) + B_k ; argmin strict < ascending k
//   residual -= q ; quantized = (q0 + q1) + q2  (elementwise fp32, ref order)
//
// ROUND 7 CHANGE: residual = 128 NAMED scalar floats, no array, no alloca.
// Residual-location history:
//   r3/r4: float r[128] + lambda        -> alloca escaped -> scratch (VGPR 104)
//   r5:    8x ext_vector(16) SSA        -> 16-wide tuple alignment -> AGPR
//          shuffling (VGPR 96, VALUBusy 53%, no win)
//   r6:    float r[128], constant idx   -> STILL scratch (VGPR 104, WRITE
//          183MB): LLVM runs SROA BEFORE full unroll; runtime-indexed alloca
//          never promoted; no post-unroll SROA pass exists.
// Named scalars are SSA at the front end — SROA irrelevant, no tuple
// constraints. Expected ~160 VGPR (3 waves/SIMD under launch_bounds(256,2)).
// Codebook rows stay wave-uniform -> s_load to SGPRs; v_fma takes 1 SGPR
// operand (legal). Tiny aa[8]/sel[3] arrays: constant-indexed, loop-free ->
// early-SROA promotes.

constexpr int kItems = 262144;
constexpr int kDim   = 128;
constexpr int kNcb   = 3;
constexpr int kK     = 256;
constexpr int kBlock = 256;

__device__ __forceinline__ float sq_rn(float x) {
    return __builtin_fmaf(x, x, 0.0f);   // single-rounded product, blocks contraction
}

// pointer version — ONLY for codebook B_k staging (reads global, no alloca)
__device__ __forceinline__ float np_sumsq128(const float* __restrict__ p) {
    float a0 = sq_rn(p[0]), a1 = sq_rn(p[1]), a2 = sq_rn(p[2]), a3 = sq_rn(p[3]),
          a4 = sq_rn(p[4]), a5 = sq_rn(p[5]), a6 = sq_rn(p[6]), a7 = sq_rn(p[7]);
    #pragma unroll
    for (int i = 8; i < 128; i += 8) {
        a0 = a0 + sq_rn(p[i + 0]); a1 = a1 + sq_rn(p[i + 1]);
        a2 = a2 + sq_rn(p[i + 2]); a3 = a3 + sq_rn(p[i + 3]);
        a4 = a4 + sq_rn(p[i + 4]); a5 = a5 + sq_rn(p[i + 5]);
        a6 = a6 + sq_rn(p[i + 6]); a7 = a7 + sq_rn(p[i + 7]);
    }
    return ((a0 + a1) + (a2 + a3)) + ((a4 + a5) + (a6 + a7));
}

// ---- 32 float4-groups of the 128 named residual scalars -------------------
#define ROWS32(M) \
  M(0,r0,r1,r2,r3)     M(1,r4,r5,r6,r7)     M(2,r8,r9,r10,r11)    M(3,r12,r13,r14,r15) \
  M(4,r16,r17,r18,r19) M(5,r20,r21,r22,r23) M(6,r24,r25,r26,r27)  M(7,r28,r29,r30,r31) \
  M(8,r32,r33,r34,r35) M(9,r36,r37,r38,r39) M(10,r40,r41,r42,r43) M(11,r44,r45,r46,r47) \
  M(12,r48,r49,r50,r51) M(13,r52,r53,r54,r55) M(14,r56,r57,r58,r59) M(15,r60,r61,r62,r63) \
  M(16,r64,r65,r66,r67) M(17,r68,r69,r70,r71) M(18,r72,r73,r74,r75) M(19,r76,r77,r78,r79) \
  M(20,r80,r81,r82,r83) M(21,r84,r85,r86,r87) M(22,r88,r89,r90,r91) M(23,r92,r93,r94,r95) \
  M(24,r96,r97,r98,r99) M(25,r100,r101,r102,r103) M(26,r104,r105,r106,r107) M(27,r108,r109,r110,r111) \
  M(28,r112,r113,r114,r115) M(29,r116,r117,r118,r119) M(30,r120,r121,r122,r123) M(31,r124,r125,r126,r127)

#define DECL4(i,a,b,c,d)  float a, b, c, d;
#define LD4(i,a,b,c,d)    { float4 v_ = xv[i]; a = v_.x; b = v_.y; c = v_.z; d = v_.w; }
#define SUB4(i,a,b,c,d)   { float4 v_ = cw4[i]; a = a - v_.x; b = b - v_.y; c = c - v_.z; d = d - v_.w; }
// A = np.sum(r*r), pairwise-8: term j adds to acc (j&7), j ascending.
// aa[] zero-init: 0 + t == t bitwise (t = square >= +0.0).
#define SQ4(i,a,b,c,d) \
  aa[(4*(i)+0)&7] = aa[(4*(i)+0)&7] + sq_rn(a); \
  aa[(4*(i)+1)&7] = aa[(4*(i)+1)&7] + sq_rn(b); \
  aa[(4*(i)+2)&7] = aa[(4*(i)+2)&7] + sq_rn(c); \
  aa[(4*(i)+3)&7] = aa[(4*(i)+3)&7] + sq_rn(d);
// sgemm K-loop: each chain m0..m3 accumulates j = 0..127 sequentially.
#define FMA4R(i,a,b,c,d) \
  m0 = __builtin_fmaf(a, c0[4*(i)+0], m0); m1 = __builtin_fmaf(a, c1[4*(i)+0], m1); \
  m2 = __builtin_fmaf(a, c2[4*(i)+0], m2); m3 = __builtin_fmaf(a, c3[4*(i)+0], m3); \
  m0 = __builtin_fmaf(b, c0[4*(i)+1], m0); m1 = __builtin_fmaf(b, c1[4*(i)+1], m1); \
  m2 = __builtin_fmaf(b, c2[4*(i)+1], m2); m3 = __builtin_fmaf(b, c3[4*(i)+1], m3); \
  m0 = __builtin_fmaf(c, c0[4*(i)+2], m0); m1 = __builtin_fmaf(c, c1[4*(i)+2], m1); \
  m2 = __builtin_fmaf(c, c2[4*(i)+2], m2); m3 = __builtin_fmaf(c, c3[4*(i)+2], m3); \
  m0 = __builtin_fmaf(d, c0[4*(i)+3], m0); m1 = __builtin_fmaf(d, c1[4*(i)+3], m1); \
  m2 = __builtin_fmaf(d, c2[4*(i)+3], m2); m3 = __builtin_fmaf(d, c3[4*(i)+3], m3);

__global__ __launch_bounds__(kBlock, 2) void rvq_kernel(
    const float* __restrict__ x,
    const float* __restrict__ cb,
    float* __restrict__ out)
{
    // B_k = np.sum(cb*cb, axis=-1), bit-exact, staged in LDS (float4 per k-group)
    __shared__ float4 s_B4[kNcb * kK / 4];
    for (int m = threadIdx.x; m < kNcb * kK; m += kBlock)
        ((float*)s_B4)[m] = np_sumsq128(cb + (size_t)m * kDim);
    __syncthreads();

    const int item = blockIdx.x * kBlock + threadIdx.x;
    const float4* xv = (const float4*)(x + (size_t)item * kDim);

    ROWS32(DECL4)          // 128 named scalar floats — pure SSA, no alloca
    ROWS32(LD4)            // residual = x

    int sel[kNcb];

    #pragma unroll
    for (int c = 0; c < kNcb; ++c) {
        const float* cbase = cb + (size_t)c * kK * kDim;

        // A = np.sum(r*r), numpy pairwise-8 scheme
        float aa[8] = {0.f, 0.f, 0.f, 0.f, 0.f, 0.f, 0.f, 0.f};
        ROWS32(SQ4)
        const float A = ((aa[0] + aa[1]) + (aa[2] + aa[3]))
                      + ((aa[4] + aa[5]) + (aa[6] + aa[7]));

        float best = INFINITY;
        int bi = 0;
        // 4 independent sequential-FMA chains; codebook rows wave-uniform
        // -> s_load to SGPRs (scalar pipe); v_fma(v, s, v) is legal.
        #pragma unroll 2
        for (int k = 0; k < kK; k += 4) {
            const float* c0 = cbase + (size_t)(k + 0) * kDim;
            const float* c1 = cbase + (size_t)(k + 1) * kDim;
            const float* c2 = cbase + (size_t)(k + 2) * kDim;
            const float* c3 = cbase + (size_t)(k + 3) * kDim;
            float m0 = 0.f, m1 = 0.f, m2 = 0.f, m3 = 0.f;
            ROWS32(FMA4R)
            const float4 b4 = s_B4[c * (kK / 4) + (k >> 2)];
            // 2.0f*m exact (exponent bump) -> bit-safe fused or not
            float t0 = (A - 2.0f * m0) + b4.x;
            float t1 = (A - 2.0f * m1) + b4.y;
            float t2 = (A - 2.0f * m2) + b4.z;
            float t3 = (A - 2.0f * m3) + b4.w;
            if (t0 < best) { best = t0; bi = k + 0; }
            if (t1 < best) { best = t1; bi = k + 1; }
            if (t2 < best) { best = t2; bi = k + 2; }
            if (t3 < best) { best = t3; bi = k + 3; }
        }
        sel[c] = bi;

        const float4* cw4 = (const float4*)(cbase + (size_t)bi * kDim);  // gather
        ROWS32(SUB4)       // residual -= q, fp32, ref element order
    }

    // --- outputs
    float* out_idx = out;                             // (items, 3) as float
    float* out_q   = out + (size_t)kItems * kNcb;     // (items, 128)
    #pragma unroll
    for (int c = 0; c < kNcb; ++c)
        out_idx[(size_t)item * kNcb + c] = (float)sel[c];

    const float* q0 = cb + ((size_t)0 * kK + sel[0]) * kDim;
    const float* q1 = cb + ((size_t)1 * kK + sel[1]) * kDim;
    const float* q2 = cb + ((size_t)2 * kK + sel[2]) * kDim;
    float* qo = out_q + (size_t)item * kDim;
    #pragma unroll
    for (int i = 0; i < kDim / 4; ++i) {
        float4 v0 = ((const float4*)q0)[i];
        float4 v1 = ((const float4*)q1)[i];
        float4 v2 = ((const float4*)q2)[i];
        float4 w;
        w.x = (v0.x + v1.x) + v2.x;
        w.y = (v0.y + v1.y) + v2.y;
        w.z = (v0.z + v1.z) + v2.z;
        w.w = (v0.w + v1.w) + v2.w;   // ((0+q0)+q1)+q2 in fp32, ref order
        ((float4*)qo)[i] = w;
    }
}

extern "C" void kernel_launch(void* const* d_in, const int* in_sizes, int n_in,
                              void* d_out, int out_size, void* d_ws, size_t ws_size,
                              hipStream_t stream) {
    const float* x  = (const float*)d_in[0];
    const float* cb = (const float*)d_in[1];
    float* out = (float*)d_out;
    rvq_kernel<<<kItems / kBlock, kBlock, 0, stream>>>(x, cb, out);
}